// Round 4
// baseline (108.441 us; speedup 1.0000x reference)
//
#include <hip/hip_runtime.h>

// out[f*N + n] = sum_d w[f*D + d] * x[n*D + d]
// F=64, N=116250, D=128, fp32 in/out. bf16 MFMA 16x16x32.
// w staged in LDS (bf16, 16B-chunk XOR swizzle). 128-thread blocks (2 waves),
// 16 n per wave; x-loads issued BEFORE the staging barrier so the HBM burst
// overlaps w-staging; bijective XCD-chunk swizzle on blockIdx.

#define NTOT 116250
#define DDIM 128
#define FILT 64

typedef __bf16 bf16x8 __attribute__((ext_vector_type(8)));
typedef float f32x4 __attribute__((ext_vector_type(4)));

__global__ __launch_bounds__(128) void
conv_dot_kernel(const float* __restrict__ x, const float* __restrict__ w,
                float* __restrict__ out) {
    __shared__ __bf16 lds_w[FILT * DDIM];   // 16 KiB, chunk c at (c ^ (row&15))

    const int tid  = threadIdx.x;
    const int wid  = tid >> 6;
    const int lane = tid & 63;
    const int lq   = lane >> 4;   // 0..3
    const int lr   = lane & 15;   // 0..15

    // ---- bijective XCD-chunk swizzle (m204): consecutive n-blocks share an XCD ----
    const int nwg = gridDim.x;
    const int q = nwg >> 3, r = nwg & 7;
    const int xcd = blockIdx.x & 7;
    const int bid = (xcd < r ? xcd * (q + 1) : r * (q + 1) + (xcd - r) * q)
                    + (blockIdx.x >> 3);

    // ---- issue the x HBM burst FIRST (independent of LDS) ----
    const int n0 = bid * 32 + wid * 16;
    int nrow = n0 + lr;
    if (nrow > NTOT - 1) nrow = NTOT - 1;        // clamp tail loads
    const float* xp = x + (size_t)nrow * DDIM + lq * 8;

    f32x4 xs[8];
#pragma unroll
    for (int kt = 0; kt < 4; ++kt) {
        xs[kt * 2]     = *reinterpret_cast<const f32x4*>(xp + kt * 32);
        xs[kt * 2 + 1] = *reinterpret_cast<const f32x4*>(xp + kt * 32 + 4);
    }

    // ---- cooperative stage: w (fp32, L2-hot) -> LDS (bf16, swizzled) ----
    // 1024 chunks of 8 bf16; 128 threads x 8 chunks.
#pragma unroll
    for (int k = 0; k < 8; ++k) {
        const int chunk = tid + k * 128;
        const int row = chunk >> 4;     // 0..63
        const int c   = chunk & 15;     // 0..15
        const float* wp = w + row * DDIM + c * 8;
        f32x4 lo = *reinterpret_cast<const f32x4*>(wp);
        f32x4 hi = *reinterpret_cast<const f32x4*>(wp + 4);
        bf16x8 v;
#pragma unroll
        for (int j = 0; j < 4; ++j) { v[j] = (__bf16)lo[j]; v[j + 4] = (__bf16)hi[j]; }
        *reinterpret_cast<bf16x8*>(&lds_w[row * DDIM + (c ^ (row & 15)) * 8]) = v;
    }
    __syncthreads();

    // ---- convert x burst to bf16 B-fragments ----
    bf16x8 bfrag[4];
#pragma unroll
    for (int kt = 0; kt < 4; ++kt) {
        bf16x8 b;
#pragma unroll
        for (int j = 0; j < 4; ++j) {
            b[j]     = (__bf16)xs[kt * 2][j];
            b[j + 4] = (__bf16)xs[kt * 2 + 1][j];
        }
        bfrag[kt] = b;
    }

    // ---- A fragments from LDS, 16 MFMA ----
    f32x4 acc[4] = {};
#pragma unroll
    for (int kt = 0; kt < 4; ++kt) {
#pragma unroll
        for (int ft = 0; ft < 4; ++ft) {
            const int row = ft * 16 + lr;
            const int csw = (kt * 4 + lq) ^ lr;   // (row&15) == lr
            bf16x8 a = *reinterpret_cast<const bf16x8*>(&lds_w[row * DDIM + csw * 8]);
            acc[ft] = __builtin_amdgcn_mfma_f32_16x16x32_bf16(a, bfrag[kt], acc[ft], 0, 0, 0);
        }
    }

    // ---- C/D layout (m89): row=(lane>>4)*4+reg -> f, col=lane&15 -> n ----
    if (n0 + lr < NTOT) {
#pragma unroll
        for (int ft = 0; ft < 4; ++ft)
#pragma unroll
            for (int j = 0; j < 4; ++j)
                out[(ft * 16 + lq * 4 + j) * NTOT + n0 + lr] = acc[ft][j];
    }
}

extern "C" void kernel_launch(void* const* d_in, const int* in_sizes, int n_in,
                              void* d_out, int out_size, void* d_ws, size_t ws_size,
                              hipStream_t stream) {
    const float* x = (const float*)d_in[0];   // (1,1,N,D) fp32
    const float* w = (const float*)d_in[1];   // (F,1,1,D) fp32
    float* out = (float*)d_out;               // (F,N) fp32 row-major
    const int blocks = (NTOT + 31) / 32;      // 32 n per block (2 waves x 16)
    conv_dot_kernel<<<blocks, 128, 0, stream>>>(x, w, out);
}

// Round 8
// 103.739 us; speedup vs baseline: 1.0453x; 1.0453x over previous
//
#include <hip/hip_runtime.h>

// out[f*N + n] = sum_d w[f*D + d] * x[n*D + d]
// F=64, N=116250, D=128, fp32 in/out. bf16 MFMA 16x16x32, SWAPPED operands:
// A = x (rows = n), B = w (cols = f)  ->  lane owns 4 consecutive n per f
// -> dwordx2 stores (8 instr/wave/tile instead of 16 scalar dwords).
// w staged once per block into LDS (bf16, 16B-chunk XOR swizzle).
// 256-thread blocks, 2 n-tiles per wave (128 n per block), x-bursts hoisted.

#define NTOT 116250
#define DDIM 128
#define FILT 64

typedef __bf16 bf16x8 __attribute__((ext_vector_type(8)));
typedef float f32x4 __attribute__((ext_vector_type(4)));
typedef float f32x2 __attribute__((ext_vector_type(2)));

__global__ __launch_bounds__(256) void
conv_dot_kernel(const float* __restrict__ x, const float* __restrict__ w,
                float* __restrict__ out) {
    __shared__ __bf16 lds_w[FILT * DDIM];   // 16 KiB, chunk c at (c ^ (row&15))

    const int tid  = threadIdx.x;
    const int wid  = tid >> 6;
    const int lane = tid & 63;
    const int lq   = lane >> 4;   // 0..3
    const int lr   = lane & 15;   // 0..15

    const int nb = blockIdx.x * 128 + wid * 32;   // wave covers 32 consecutive n

    // ---- hoist BOTH tiles' x HBM bursts above staging (independent of LDS) ----
    f32x4 xs[2][8];
#pragma unroll
    for (int t = 0; t < 2; ++t) {
        int nrow = nb + t * 16 + lr;
        if (nrow > NTOT - 1) nrow = NTOT - 1;     // clamp tail loads
        const float* xp = x + (size_t)nrow * DDIM + lq * 8;
#pragma unroll
        for (int kt = 0; kt < 4; ++kt) {
            xs[t][kt * 2]     = *reinterpret_cast<const f32x4*>(xp + kt * 32);
            xs[t][kt * 2 + 1] = *reinterpret_cast<const f32x4*>(xp + kt * 32 + 4);
        }
    }

    // ---- cooperative stage: w (fp32, L2-hot) -> LDS (bf16, swizzled) ----
    // 1024 chunks of 8 bf16; 256 threads x 4 chunks.
#pragma unroll
    for (int k = 0; k < 4; ++k) {
        const int chunk = tid + k * 256;
        const int row = chunk >> 4;     // f: 0..63
        const int c   = chunk & 15;     // 0..15
        const float* wp = w + row * DDIM + c * 8;
        f32x4 lo = *reinterpret_cast<const f32x4*>(wp);
        f32x4 hi = *reinterpret_cast<const f32x4*>(wp + 4);
        bf16x8 v;
#pragma unroll
        for (int j = 0; j < 4; ++j) { v[j] = (__bf16)lo[j]; v[j + 4] = (__bf16)hi[j]; }
        *reinterpret_cast<bf16x8*>(&lds_w[row * DDIM + (c ^ (row & 15)) * 8]) = v;
    }
    __syncthreads();

    // ---- per tile: cvt x, 16 MFMA (A=x, B=w from LDS), dwordx2 stores ----
#pragma unroll
    for (int t = 0; t < 2; ++t) {
        bf16x8 xf[4];
#pragma unroll
        for (int kt = 0; kt < 4; ++kt) {
            bf16x8 b;
#pragma unroll
            for (int j = 0; j < 4; ++j) {
                b[j]     = (__bf16)xs[t][kt * 2][j];
                b[j + 4] = (__bf16)xs[t][kt * 2 + 1][j];
            }
            xf[kt] = b;
        }

        f32x4 acc[4] = {};
#pragma unroll
        for (int kt = 0; kt < 4; ++kt) {
#pragma unroll
            for (int ft = 0; ft < 4; ++ft) {
                const int row = ft * 16 + lr;                 // f
                const int csw = (kt * 4 + lq) ^ lr;           // (row&15) == lr
                bf16x8 wf = *reinterpret_cast<const bf16x8*>(&lds_w[row * DDIM + csw * 8]);
                acc[ft] = __builtin_amdgcn_mfma_f32_16x16x32_bf16(xf[kt], wf, acc[ft], 0, 0, 0);
            }
        }

        // D layout (m89): row = lq*4+reg -> n (A side), col = lr -> f (B side).
        // lane holds out[f = ft*16+lr][n0t + lq*4 + 0..3] -> two float2 stores.
        const int n0t = nb + t * 16;
        if (n0t + 15 < NTOT) {
#pragma unroll
            for (int ft = 0; ft < 4; ++ft) {
                float* p = out + (size_t)(ft * 16 + lr) * NTOT + n0t + lq * 4;
                f32x2 v01; v01[0] = acc[ft][0]; v01[1] = acc[ft][1];
                f32x2 v23; v23[0] = acc[ft][2]; v23[1] = acc[ft][3];
                *reinterpret_cast<f32x2*>(p)     = v01;
                *reinterpret_cast<f32x2*>(p + 2) = v23;
            }
        } else {
#pragma unroll
            for (int ft = 0; ft < 4; ++ft)
#pragma unroll
                for (int j = 0; j < 4; ++j) {
                    const int n = n0t + lq * 4 + j;
                    if (n < NTOT)
                        out[(size_t)(ft * 16 + lr) * NTOT + n] = acc[ft][j];
                }
        }
    }
}

extern "C" void kernel_launch(void* const* d_in, const int* in_sizes, int n_in,
                              void* d_out, int out_size, void* d_ws, size_t ws_size,
                              hipStream_t stream) {
    const float* x = (const float*)d_in[0];   // (1,1,N,D) fp32
    const float* w = (const float*)d_in[1];   // (F,1,1,D) fp32
    float* out = (float*)d_out;               // (F,N) fp32 row-major
    const int blocks = (NTOT + 127) / 128;    // 128 n per block (4 waves x 2 x 16)
    conv_dot_kernel<<<blocks, 256, 0, stream>>>(x, w, out);
}